// Round 4
// baseline (706.389 us; speedup 1.0000x reference)
//
#include <hip/hip_runtime.h>
#include <cmath>

#define BB 4
#define LL 2048
#define DD 1024
#define HH 8
#define MM (BB * LL)   // 8192 rows

struct Gammas { float lg2[8]; };
struct MMArgs { const ushort* Bt[4]; void* C[4]; int emode[4]; };

typedef __attribute__((ext_vector_type(8))) short bf16x8;
typedef __attribute__((ext_vector_type(4))) float f32x4;

__device__ __forceinline__ ushort f2bf(float f) {
    uint u = __builtin_bit_cast(uint, f);
    uint r = (u + 0x7fffu + ((u >> 16) & 1u)) >> 16;
    return (ushort)r;
}
__device__ __forceinline__ float bf2f(ushort h) {
    uint u = ((uint)h) << 16;
    return __builtin_bit_cast(float, u);
}
__device__ __forceinline__ void gload16(const void* g, void* l) {
    __builtin_amdgcn_global_load_lds((const __attribute__((address_space(1))) void*)g,
                                     (__attribute__((address_space(3))) void*)l, 16, 0, 0);
}

// ---------------------------------------------------------------------------
// xpos table: tbl[l*64 + i] = {cos*scale, sin*scale, cos/scale, sin/scale}
// ---------------------------------------------------------------------------
__global__ void xpos_table_kernel(float4* __restrict__ tbl) {
    int tid = blockIdx.x * blockDim.x + threadIdx.x;
    if (tid >= LL * 64) return;
    int l = tid >> 6, i = tid & 63;
    float inv = powf(10000.0f, -(float)i / 64.0f);
    float ang = (float)l * inv;
    float s = sinf(ang), c = cosf(ang);
    float base = (2.0f * (float)i + 51.2f) / 179.2f;
    float sc = powf(base, (float)l / 512.0f);
    tbl[tid] = make_float4(c * sc, s * sc, c / sc, s / sc);
}

__global__ __launch_bounds__(256) void cast_kernel(const float* __restrict__ X,
                                                   ushort* __restrict__ Xb) {
    int i = (blockIdx.x * 256 + threadIdx.x) * 4;
    float4 v = *(const float4*)&X[i];
    ushort4 o;
    o.x = f2bf(v.x); o.y = f2bf(v.y); o.z = f2bf(v.z); o.w = f2bf(v.w);
    *(ushort4*)&Xb[i] = o;
}

// ---------------------------------------------------------------------------
// Weight transpose+cast: W[k][n] (flat or per-head (h,d,e)) -> Wt[n][k] bf16
// ---------------------------------------------------------------------------
__global__ __launch_bounds__(256) void wtrans_kernel(const float* __restrict__ W,
                                                     ushort* __restrict__ Wt, int perhead) {
    __shared__ float T[64][68];
    const int k0 = blockIdx.y * 64, n0 = blockIdx.x * 64;
    const int t = threadIdx.x;
    for (int f = t; f < 64 * 16; f += 256) {
        int kk = f >> 4, s = f & 15;
        int n = n0 + s * 4;
        size_t src = perhead ? (size_t)(n >> 7) * 131072 + (size_t)(k0 + kk) * 128 + (n & 127)
                             : (size_t)(k0 + kk) * 1024 + n;
        *(float4*)&T[kk][s * 4] = *(const float4*)&W[src];
    }
    __syncthreads();
    for (int f = t; f < 64 * 8; f += 256) {
        int n = f >> 3, s = f & 7;
        __align__(16) ushort tmp[8];
        #pragma unroll
        for (int j = 0; j < 8; j++) tmp[j] = f2bf(T[s * 8 + j][n]);
        *(uint4*)&Wt[(size_t)(n0 + n) * 1024 + k0 + s * 8] = *(uint4*)tmp;
    }
}

// ---------------------------------------------------------------------------
// bf16 MFMA GEMM: C = A[8192x1024] * Bt^T, multi-output (4 weight/out sets).
// LDS tiles use a 16B-granule XOR swizzle (granule ^ ((row>>1)&3)) applied to
// the GLOBAL source address (global_load_lds lane->LDS mapping is fixed).
// emode: 1 xpos up->bf16, 2 xpos down->bf16, 3 silu->bf16, 4 plain->fp32,
//        5 V-transposed store (Vt[b][v][l] bf16)
// ---------------------------------------------------------------------------
__global__ __launch_bounds__(256) void mm_kernel(
    const ushort* __restrict__ A, MMArgs args, const float4* __restrict__ tbl)
{
    __shared__ __align__(16) ushort As[128 * 32];
    __shared__ __align__(16) ushort Bs[128 * 32];
    const int t = threadIdx.x;
    const int w = t >> 6, lane = t & 63;
    const int ln = lane & 15, quad = lane >> 4;
    const int which = blockIdx.x >> 3;
    const ushort* Bt = args.Bt[which];
    void* Cv = args.C[which];
    const int emode = args.emode[which];
    const int n0 = (blockIdx.x & 7) * 128, m0 = blockIdx.y * 128;
    const int wm = w & 1, wn = w >> 1;

    f32x4 acc[4][4];
    const f32x4 fzero = {0.f, 0.f, 0.f, 0.f};
    #pragma unroll
    for (int i = 0; i < 4; i++)
        #pragma unroll
        for (int j = 0; j < 4; j++) acc[i][j] = fzero;

    const int srow = w * 32 + (lane >> 2);
    // swizzled source granule: lane's LDS slot (row=srow, gp=lane&3) must hold
    // logical granule gl = gp ^ ((row>>1)&3) = (lane&3) ^ ((lane>>3)&3)
    const int scol = (((lane & 3) ^ ((lane >> 3) & 3))) * 8;
    const ushort* ga  = A  + (size_t)(m0 + srow) * 1024 + scol;
    const ushort* ga2 = ga + 16 * 1024;
    const ushort* gb  = Bt + (size_t)(n0 + srow) * 1024 + scol;
    const ushort* gb2 = gb + 16 * 1024;
    ushort* la  = &As[(w * 32) * 32];
    ushort* la2 = &As[(w * 32 + 16) * 32];
    ushort* lb  = &Bs[(w * 32) * 32];
    ushort* lb2 = &Bs[(w * 32 + 16) * 32];

    const int fsw = (quad ^ ((ln >> 1) & 3)) * 8;   // swizzled frag col

    for (int kt = 0; kt < 1024; kt += 32) {
        gload16(ga + kt, la);
        gload16(ga2 + kt, la2);
        gload16(gb + kt, lb);
        gload16(gb2 + kt, lb2);
        __syncthreads();
        bf16x8 am[4], bn[4];
        #pragma unroll
        for (int i = 0; i < 4; i++)
            am[i] = *(const bf16x8*)&As[(wm * 64 + i * 16 + ln) * 32 + fsw];
        #pragma unroll
        for (int i = 0; i < 4; i++)
            bn[i] = *(const bf16x8*)&Bs[(wn * 64 + i * 16 + ln) * 32 + fsw];
        #pragma unroll
        for (int mi = 0; mi < 4; mi++)
            #pragma unroll
            for (int ni = 0; ni < 4; ni++)
                acc[mi][ni] = __builtin_amdgcn_mfma_f32_16x16x32_bf16(
                    am[mi], bn[ni], acc[mi][ni], 0, 0, 0);
        __syncthreads();
    }

    #pragma unroll
    for (int mi = 0; mi < 4; mi++) {
        #pragma unroll
        for (int ni = 0; ni < 4; ni++) {
            const int row0 = m0 + wm * 64 + mi * 16 + quad * 4;
            const int e = wn * 64 + ni * 16 + ln;       // col within head
            const int col = n0 + e;
            if (emode == 5) {
                const int b = row0 >> 11, l0 = row0 & (LL - 1);
                ushort4 pk;
                pk.x = f2bf(acc[mi][ni][0]); pk.y = f2bf(acc[mi][ni][1]);
                pk.z = f2bf(acc[mi][ni][2]); pk.w = f2bf(acc[mi][ni][3]);
                *(ushort4*)&((ushort*)Cv)[((size_t)(b * 1024 + col)) * 2048 + l0] = pk;
                continue;
            }
            #pragma unroll
            for (int r = 0; r < 4; r++) {
                float v = acc[mi][ni][r];
                if (emode == 1 || emode == 2) {
                    float4 tt = tbl[(size_t)((row0 + r) & (LL - 1)) * 64 + (e >> 1)];
                    float cc = (emode == 1) ? tt.x : tt.z;
                    float ss = (emode == 1) ? tt.y : tt.w;
                    float partner = __shfl_xor(v, 1);
                    float rot = (e & 1) ? partner : -partner;
                    v = v * cc + rot * ss;
                } else if (emode == 3) {
                    v = v / (1.0f + expf(-v));
                }
                if (emode == 4)
                    ((float*)Cv)[(size_t)(row0 + r) * 1024 + col] = v;
                else
                    ((ushort*)Cv)[(size_t)(row0 + r) * 1024 + col] = f2bf(v);
            }
        }
    }
}

// ---------------------------------------------------------------------------
// Retention (MFMA) + fused groupnorm/gate. One query-block per block
// (1024 blocks, heavy-first). LDS = 40 KB exactly (XOR-swizzled, no padding)
// -> 4 blocks/CU. S^T via swapped-operand MFMA; K/V register-prefetched.
// Epilogue: per-row mean/var via 16-lane shfl, gate with silu(G), store bf16 Z.
// ---------------------------------------------------------------------------
__global__ __launch_bounds__(256) void ret_kernel(
    const ushort* __restrict__ Qb, const ushort* __restrict__ Kb,
    const ushort* __restrict__ Vt, const ushort* __restrict__ Gb,
    const float* __restrict__ gnw, const float* __restrict__ gnb,
    ushort* __restrict__ Zb, Gammas gp)
{
    __shared__ __align__(16) ushort Ks[64 * 128];   // 16 KB  (row=key, 16 granules)
    __shared__ __align__(16) ushort Vs[128 * 64];   // 16 KB  (row=vcol, 8 granules)
    __shared__ __align__(16) ushort Ss[64 * 64];    //  8 KB  (row=query, 8 granules)

    const int t = threadIdx.x;
    const int w = t >> 6, lane = t & 63, ln = lane & 15, quad = lane >> 4;
    const int qb = 31 - blockIdx.x;            // heavy blocks first
    const int n0 = qb * 64;
    const int bh = blockIdx.y, b = bh >> 3, h = bh & 7;
    const float lg2 = gp.lg2[h];
    const size_t qkbase = (size_t)b * LL * 1024 + (size_t)h * 128;
    const size_t vtbase = ((size_t)b * 1024 + h * 128) * 2048;

    const int cap = (int)((34.0f / (-lg2) + 63.0f) * 0.015625f);

    float dmk[4], drr[4];
    #pragma unroll
    for (int kt = 0; kt < 4; kt++)
        dmk[kt] = exp2f(-(float)(kt * 16 + quad * 4) * lg2);
    #pragma unroll
    for (int r = 0; r < 4; r++)
        drr[r] = exp2f(-(float)r * lg2);

    // staging indices + swizzled LDS write offsets
    const int krow = t >> 4, kgl = t & 15;          // K: rows krow+16i, granule kgl
    const int vrow = t >> 3, vgl = t & 7;           // V: rows vrow+32i, granule vgl
    const int kwoff = (kgl ^ (krow & 7)) * 8;
    const int vwoff = (vgl ^ (vrow & 7)) * 8;

    bf16x8 aq[4];
    #pragma unroll
    for (int ks = 0; ks < 4; ks++)
        aq[ks] = *(const bf16x8*)&Qb[qkbase + (size_t)(n0 + 16 * w + ln) * 1024
                                     + ks * 32 + quad * 8];
    f32x4 y[8];
    const f32x4 fzero = {0.f, 0.f, 0.f, 0.f};
    #pragma unroll
    for (int vt = 0; vt < 8; vt++) y[vt] = fzero;

    int cmin = qb - cap; if (cmin < 0) cmin = 0;

    uint4 kreg[4], vreg[4];
    {
        const int m0 = cmin * 64;
        #pragma unroll
        for (int i = 0; i < 4; i++)
            kreg[i] = *(const uint4*)&Kb[qkbase + (size_t)(m0 + krow + i * 16) * 1024 + kgl * 8];
        #pragma unroll
        for (int i = 0; i < 4; i++)
            vreg[i] = *(const uint4*)&Vt[vtbase + (size_t)(vrow + i * 32) * 2048 + m0 + vgl * 8];
    }

    for (int c = cmin; c <= qb; c++) {
        const int m0 = c * 64;
        __syncthreads();
        #pragma unroll
        for (int i = 0; i < 4; i++)
            *(uint4*)&Ks[(krow + i * 16) * 128 + kwoff] = kreg[i];
        #pragma unroll
        for (int i = 0; i < 4; i++)
            *(uint4*)&Vs[(vrow + i * 32) * 64 + vwoff] = vreg[i];
        __syncthreads();
        if (c < qb) {
            const int m1 = m0 + 64;
            #pragma unroll
            for (int i = 0; i < 4; i++)
                kreg[i] = *(const uint4*)&Kb[qkbase + (size_t)(m1 + krow + i * 16) * 1024 + kgl * 8];
            #pragma unroll
            for (int i = 0; i < 4; i++)
                vreg[i] = *(const uint4*)&Vt[vtbase + (size_t)(vrow + i * 32) * 2048 + m1 + vgl * 8];
        }

        // S^T: mfma(bk, aq) -> lane holds S[n=16w+ln][m=kt*16+quad*4+r]
        f32x4 s4[4];
        #pragma unroll
        for (int kt = 0; kt < 4; kt++) s4[kt] = fzero;
        #pragma unroll
        for (int ks = 0; ks < 4; ks++) {
            #pragma unroll
            for (int kt = 0; kt < 4; kt++) {
                bf16x8 bk = *(const bf16x8*)&Ks[(kt * 16 + ln) * 128
                                                + (((ks * 4 + quad) ^ (ln & 7)) * 8)];
                s4[kt] = __builtin_amdgcn_mfma_f32_16x16x32_bf16(bk, aq[ks], s4[kt], 0, 0, 0);
            }
        }

        const float dq = exp2f((float)(n0 - m0 + 16 * w + ln) * lg2);
        #pragma unroll
        for (int kt = 0; kt < 4; kt++) {
            const float db = dq * dmk[kt];
            ushort4 pk;
            if (c == qb) {
                pk.x = f2bf((kt * 16 + quad * 4 + 0 <= 16 * w + ln) ? s4[kt][0] * db * drr[0] : 0.f);
                pk.y = f2bf((kt * 16 + quad * 4 + 1 <= 16 * w + ln) ? s4[kt][1] * db * drr[1] : 0.f);
                pk.z = f2bf((kt * 16 + quad * 4 + 2 <= 16 * w + ln) ? s4[kt][2] * db * drr[2] : 0.f);
                pk.w = f2bf((kt * 16 + quad * 4 + 3 <= 16 * w + ln) ? s4[kt][3] * db * drr[3] : 0.f);
            } else {
                pk.x = f2bf(s4[kt][0] * db * drr[0]);
                pk.y = f2bf(s4[kt][1] * db * drr[1]);
                pk.z = f2bf(s4[kt][2] * db * drr[2]);
                pk.w = f2bf(s4[kt][3] * db * drr[3]);
            }
            // logical granule 2kt+(quad>>1), sub-8B (quad&1)
            *(ushort4*)&Ss[(16 * w + ln) * 64
                           + (((2 * kt + (quad >> 1)) ^ (ln & 7)) * 8) + (quad & 1) * 4] = pk;
        }

        // Y += S * V   (Ss rows are wave-private: no barrier needed)
        #pragma unroll
        for (int ks2 = 0; ks2 < 2; ks2++) {
            bf16x8 as = *(const bf16x8*)&Ss[(16 * w + ln) * 64
                                            + (((ks2 * 4 + quad) ^ (ln & 7)) * 8)];
            #pragma unroll
            for (int vt = 0; vt < 8; vt++) {
                bf16x8 bv = *(const bf16x8*)&Vs[(vt * 16 + ln) * 64
                                                + (((ks2 * 4 + quad) ^ (ln & 7)) * 8)];
                y[vt] = __builtin_amdgcn_mfma_f32_16x16x32_bf16(as, bv, y[vt], 0, 0, 0);
            }
        }
    }

    // fused groupnorm + gate epilogue (row's 128 v-values live in 16-lane group)
    #pragma unroll
    for (int r = 0; r < 4; r++) {
        float s = 0.f, sq = 0.f;
        #pragma unroll
        for (int vt = 0; vt < 8; vt++) {
            float v = y[vt][r];
            s += v; sq += v * v;
        }
        #pragma unroll
        for (int off = 8; off >= 1; off >>= 1) {
            s  += __shfl_xor(s, off);
            sq += __shfl_xor(sq, off);
        }
        float mean = s * 0.0078125f;
        float var = sq * 0.0078125f - mean * mean;
        float rstd = rsqrtf(var + 1e-5f);
        const int row = n0 + 16 * w + quad * 4 + r;
        const size_t obase = (size_t)(b * LL + row) * 1024 + h * 128;
        #pragma unroll
        for (int vt = 0; vt < 8; vt++) {
            const int e = vt * 16 + ln;
            float gate = bf2f(Gb[obase + e]);
            float z = ((y[vt][r] - mean) * rstd * gnw[h * 128 + e] + gnb[h * 128 + e]) * gate;
            Zb[obase + e] = f2bf(z);
        }
    }
}

// ---------------------------------------------------------------------------
extern "C" void kernel_launch(void* const* d_in, const int* in_sizes, int n_in,
                              void* d_out, int out_size, void* d_ws, size_t ws_size,
                              hipStream_t stream) {
    const float* X   = (const float*)d_in[0];
    const float* Wq  = (const float*)d_in[1];
    const float* Wk  = (const float*)d_in[2];
    const float* Wv  = (const float*)d_in[3];
    const float* Wg  = (const float*)d_in[4];
    const float* Wo  = (const float*)d_in[5];
    const float* gnw = (const float*)d_in[6];
    const float* gnb = (const float*)d_in[7];
    float* out = (float*)d_out;

    const size_t MB = 1u << 20;
    char* base = (char*)d_ws;
    float4* tbl = (float4*)base;                        // 2 MB
    ushort* Xb  = (ushort*)(base + 2 * MB);             // 16 MB
    ushort* Wqt = (ushort*)(base + 18 * MB);
    ushort* Wkt = (ushort*)(base + 20 * MB);
    ushort* Wvt = (ushort*)(base + 22 * MB);
    ushort* Wgt = (ushort*)(base + 24 * MB);
    ushort* Wot = (ushort*)(base + 26 * MB);
    ushort* Qb  = (ushort*)(base + 28 * MB);            // 16 MB (later Z)
    ushort* Kb  = (ushort*)(base + 44 * MB);            // 16 MB
    ushort* Gb  = (ushort*)(base + 60 * MB);            // 16 MB (silu applied)
    ushort* Vt  = (ushort*)(base + 76 * MB);            // 16 MB -> 92 MB
    ushort* Zb  = Qb;

    Gammas gp;
    for (int h = 0; h < 8; h++) {
        double lin = log(1.0 / 32.0) +
                     (log(1.0 / 512.0) - log(1.0 / 32.0)) * (double)h / 7.0;
        float gamma = 1.0f - expf((float)lin);
        gp.lg2[h] = log2f(gamma);
    }

    xpos_table_kernel<<<(LL * 64) / 256, 256, 0, stream>>>(tbl);
    cast_kernel<<<MM * 1024 / 1024, 256, 0, stream>>>(X, Xb);

    dim3 wgrid(16, 16);
    wtrans_kernel<<<wgrid, 256, 0, stream>>>(Wq, Wqt, 1);
    wtrans_kernel<<<wgrid, 256, 0, stream>>>(Wk, Wkt, 1);
    wtrans_kernel<<<wgrid, 256, 0, stream>>>(Wv, Wvt, 1);
    wtrans_kernel<<<wgrid, 256, 0, stream>>>(Wg, Wgt, 0);
    wtrans_kernel<<<wgrid, 256, 0, stream>>>(Wo, Wot, 0);

    // fused Q/K/V/G projections (V written directly transposed into Vt)
    MMArgs qa;
    qa.Bt[0] = Wqt; qa.Bt[1] = Wkt; qa.Bt[2] = Wvt; qa.Bt[3] = Wgt;
    qa.C[0] = Qb;   qa.C[1] = Kb;   qa.C[2] = Vt;   qa.C[3] = Gb;
    qa.emode[0] = 1; qa.emode[1] = 2; qa.emode[2] = 5; qa.emode[3] = 3;
    mm_kernel<<<dim3(32, 64), 256, 0, stream>>>(Xb, qa, tbl);

    // retention + fused groupnorm/gate -> Zb (bf16, overwrites Qb region)
    ret_kernel<<<dim3(32, 32), 256, 0, stream>>>(Qb, Kb, Vt, Gb, gnw, gnb, Zb, gp);

    MMArgs oa;
    oa.Bt[0] = Wot; oa.Bt[1] = Wot; oa.Bt[2] = Wot; oa.Bt[3] = Wot;
    oa.C[0] = out;  oa.C[1] = out;  oa.C[2] = out;  oa.C[3] = out;
    oa.emode[0] = 4; oa.emode[1] = 4; oa.emode[2] = 4; oa.emode[3] = 4;
    mm_kernel<<<dim3(8, 64), 256, 0, stream>>>(Zb, oa, tbl);
}

// Round 5
// 696.705 us; speedup vs baseline: 1.0139x; 1.0139x over previous
//
#include <hip/hip_runtime.h>
#include <cmath>

#define BB 4
#define LL 2048
#define DD 1024
#define HH 8
#define MM (BB * LL)   // 8192 rows

struct Gammas { float lg2[8]; };
struct MMArgs { const ushort* Bt[4]; void* C[4]; int emode[4]; };

typedef __attribute__((ext_vector_type(8))) short bf16x8;
typedef __attribute__((ext_vector_type(4))) float f32x4;

__device__ __forceinline__ ushort f2bf(float f) {
    uint u = __builtin_bit_cast(uint, f);
    uint r = (u + 0x7fffu + ((u >> 16) & 1u)) >> 16;
    return (ushort)r;
}
__device__ __forceinline__ float bf2f(ushort h) {
    uint u = ((uint)h) << 16;
    return __builtin_bit_cast(float, u);
}
__device__ __forceinline__ void gload16(const void* g, void* l) {
    __builtin_amdgcn_global_load_lds((const __attribute__((address_space(1))) void*)g,
                                     (__attribute__((address_space(3))) void*)l, 16, 0, 0);
}

// ---------------------------------------------------------------------------
// xpos table: tbl[l*64 + i] = {cos*scale, sin*scale, cos/scale, sin/scale}
// ---------------------------------------------------------------------------
__global__ void xpos_table_kernel(float4* __restrict__ tbl) {
    int tid = blockIdx.x * blockDim.x + threadIdx.x;
    if (tid >= LL * 64) return;
    int l = tid >> 6, i = tid & 63;
    float inv = powf(10000.0f, -(float)i / 64.0f);
    float ang = (float)l * inv;
    float s = sinf(ang), c = cosf(ang);
    float base = (2.0f * (float)i + 51.2f) / 179.2f;
    float sc = powf(base, (float)l / 512.0f);
    tbl[tid] = make_float4(c * sc, s * sc, c / sc, s / sc);
}

__global__ __launch_bounds__(256) void cast_kernel(const float* __restrict__ X,
                                                   ushort* __restrict__ Xb) {
    int i = (blockIdx.x * 256 + threadIdx.x) * 4;
    float4 v = *(const float4*)&X[i];
    ushort4 o;
    o.x = f2bf(v.x); o.y = f2bf(v.y); o.z = f2bf(v.z); o.w = f2bf(v.w);
    *(ushort4*)&Xb[i] = o;
}

// ---------------------------------------------------------------------------
// Weight transpose+cast: W[k][n] (flat or per-head (h,d,e)) -> Wt[n][k] bf16
// ---------------------------------------------------------------------------
__global__ __launch_bounds__(256) void wtrans_kernel(const float* __restrict__ W,
                                                     ushort* __restrict__ Wt, int perhead) {
    __shared__ float T[64][68];
    const int k0 = blockIdx.y * 64, n0 = blockIdx.x * 64;
    const int t = threadIdx.x;
    for (int f = t; f < 64 * 16; f += 256) {
        int kk = f >> 4, s = f & 15;
        int n = n0 + s * 4;
        size_t src = perhead ? (size_t)(n >> 7) * 131072 + (size_t)(k0 + kk) * 128 + (n & 127)
                             : (size_t)(k0 + kk) * 1024 + n;
        *(float4*)&T[kk][s * 4] = *(const float4*)&W[src];
    }
    __syncthreads();
    for (int f = t; f < 64 * 8; f += 256) {
        int n = f >> 3, s = f & 7;
        __align__(16) ushort tmp[8];
        #pragma unroll
        for (int j = 0; j < 8; j++) tmp[j] = f2bf(T[s * 8 + j][n]);
        *(uint4*)&Wt[(size_t)(n0 + n) * 1024 + k0 + s * 8] = *(uint4*)tmp;
    }
}

// ---------------------------------------------------------------------------
// bf16 MFMA GEMM: C = A[8192x1024] * Bt^T, multi-output (4 weight/out sets).
// LDS tiles XOR-swizzled via the GLOBAL source address (gload mapping fixed).
// emode: 1 xpos up -> Q plain bf16
//        2 xpos down -> K_sw swizzled per-(b,h) [key][slot] layout
//        3 silu -> plain bf16
//        4 plain -> fp32
//        5 V -> Vt_sw [b][vcol][chunk][slot] swizzled transposed layout
// ---------------------------------------------------------------------------
__global__ __launch_bounds__(256) void mm_kernel(
    const ushort* __restrict__ A, MMArgs args, const float4* __restrict__ tbl)
{
    __shared__ __align__(16) ushort As[128 * 32];
    __shared__ __align__(16) ushort Bs[128 * 32];
    const int t = threadIdx.x;
    const int w = t >> 6, lane = t & 63;
    const int ln = lane & 15, quad = lane >> 4;
    const int which = blockIdx.x >> 3;
    const ushort* Bt = args.Bt[which];
    void* Cv = args.C[which];
    const int emode = args.emode[which];
    const int n0 = (blockIdx.x & 7) * 128, m0 = blockIdx.y * 128;
    const int wm = w & 1, wn = w >> 1;

    f32x4 acc[4][4];
    const f32x4 fzero = {0.f, 0.f, 0.f, 0.f};
    #pragma unroll
    for (int i = 0; i < 4; i++)
        #pragma unroll
        for (int j = 0; j < 4; j++) acc[i][j] = fzero;

    const int srow = w * 32 + (lane >> 2);
    const int scol = (((lane & 3) ^ ((lane >> 3) & 3))) * 8;   // source swizzle
    const ushort* ga  = A  + (size_t)(m0 + srow) * 1024 + scol;
    const ushort* ga2 = ga + 16 * 1024;
    const ushort* gb  = Bt + (size_t)(n0 + srow) * 1024 + scol;
    const ushort* gb2 = gb + 16 * 1024;
    ushort* la  = &As[(w * 32) * 32];
    ushort* la2 = &As[(w * 32 + 16) * 32];
    ushort* lb  = &Bs[(w * 32) * 32];
    ushort* lb2 = &Bs[(w * 32 + 16) * 32];

    const int fsw = (quad ^ ((ln >> 1) & 3)) * 8;   // swizzled frag col

    for (int kt = 0; kt < 1024; kt += 32) {
        gload16(ga + kt, la);
        gload16(ga2 + kt, la2);
        gload16(gb + kt, lb);
        gload16(gb2 + kt, lb2);
        __syncthreads();
        bf16x8 am[4], bn[4];
        #pragma unroll
        for (int i = 0; i < 4; i++)
            am[i] = *(const bf16x8*)&As[(wm * 64 + i * 16 + ln) * 32 + fsw];
        #pragma unroll
        for (int i = 0; i < 4; i++)
            bn[i] = *(const bf16x8*)&Bs[(wn * 64 + i * 16 + ln) * 32 + fsw];
        #pragma unroll
        for (int mi = 0; mi < 4; mi++)
            #pragma unroll
            for (int ni = 0; ni < 4; ni++)
                acc[mi][ni] = __builtin_amdgcn_mfma_f32_16x16x32_bf16(
                    am[mi], bn[ni], acc[mi][ni], 0, 0, 0);
        __syncthreads();
    }

    #pragma unroll
    for (int mi = 0; mi < 4; mi++) {
        #pragma unroll
        for (int ni = 0; ni < 4; ni++) {
            const int row0 = m0 + wm * 64 + mi * 16 + quad * 4;
            const int e = wn * 64 + ni * 16 + ln;
            const int col = n0 + e;
            if (emode == 5) {
                // V transposed + chunk-swizzled: key l0..l0+3 in one granule
                const int bb2 = row0 >> 11, l0 = row0 & (LL - 1);
                const int slot = ((l0 >> 3) & 7) ^ (col & 7);
                ushort4 pk;
                pk.x = f2bf(acc[mi][ni][0]); pk.y = f2bf(acc[mi][ni][1]);
                pk.z = f2bf(acc[mi][ni][2]); pk.w = f2bf(acc[mi][ni][3]);
                *(ushort4*)&((ushort*)Cv)[((size_t)(bb2 * 1024 + col)) * 2048
                                          + (l0 & ~63) + slot * 8 + (l0 & 7)] = pk;
                continue;
            }
            #pragma unroll
            for (int r = 0; r < 4; r++) {
                float v = acc[mi][ni][r];
                if (emode == 1 || emode == 2) {
                    float4 tt = tbl[(size_t)((row0 + r) & (LL - 1)) * 64 + (e >> 1)];
                    float cc = (emode == 1) ? tt.x : tt.z;
                    float ss = (emode == 1) ? tt.y : tt.w;
                    float partner = __shfl_xor(v, 1);
                    float rot = (e & 1) ? partner : -partner;
                    v = v * cc + rot * ss;
                } else if (emode == 3) {
                    v = v / (1.0f + expf(-v));
                }
                if (emode == 4) {
                    ((float*)Cv)[(size_t)(row0 + r) * 1024 + col] = v;
                } else if (emode == 2) {
                    // K swizzled per-(b,h): [key][slot]
                    const int grow = row0 + r;
                    const int bb2 = grow >> 11, l = grow & (LL - 1);
                    const int hh = col >> 7, eh = col & 127;
                    ((ushort*)Cv)[((size_t)(bb2 * 8 + hh) * 2048 + l) * 128
                                  + (size_t)(((eh >> 3) ^ (l & 7)) * 8) + (eh & 7)] = f2bf(v);
                } else {
                    ((ushort*)Cv)[(size_t)(row0 + r) * 1024 + col] = f2bf(v);
                }
            }
        }
    }
}

// ---------------------------------------------------------------------------
// Retention (MFMA) + fused groupnorm/gate.
// M=128 queries/block, 64-key chunks. K/V staged via global_load_lds from
// pre-swizzled global layouts (no ds_writes for staging). LDS 48KB exactly
// -> 3 blocks/CU. Complementary qb pairing keeps per-CU work ~constant.
// ---------------------------------------------------------------------------
__global__ __launch_bounds__(256, 3) void ret_kernel(
    const ushort* __restrict__ Qb, const ushort* __restrict__ Ksw,
    const ushort* __restrict__ Vsw, const ushort* __restrict__ Gb,
    const float* __restrict__ gnw, const float* __restrict__ gnb,
    ushort* __restrict__ Zb, Gammas gp)
{
    __shared__ __align__(16) ushort smem[24576];   // 48 KB
    ushort* Ks = smem;                // 64 keys x 128 el (16 slots)   16 KB
    ushort* Vs = smem + 8192;         // 128 vcol x 64 keys (8 slots)  16 KB
    ushort* Ss = smem + 16384;        // 4 waves x 32 rows x 64 keys   16 KB
    ushort* Zs = smem + 16384;        // epilogue alias: 64 rows x 128 16 KB

    const int t = threadIdx.x;
    const int w = t >> 6, lane = t & 63, ln = lane & 15, quad = lane >> 4;

    // balanced mapping: linear n and n+256 get complementary qb
    const int n = blockIdx.x + (blockIdx.y << 4);
    const int half = n >> 8, m8 = n & 255;
    const int qb = half ? (m8 & 15) : 15 - (m8 & 15);
    const int bh = (m8 >> 4) + (half << 4);
    const int b = bh >> 3, h = bh & 7;
    const int n0 = qb * 128;
    const float lg2 = gp.lg2[h];

    const size_t qbase = (size_t)(b * LL) * 1024 + (size_t)h * 128;
    const size_t kbase = (size_t)bh * (2048 * 128);
    const size_t vbase = ((size_t)b * 1024 + h * 128) * 2048;

    float dmk[4], drr[4];
    #pragma unroll
    for (int kt = 0; kt < 4; kt++)
        dmk[kt] = exp2f(-(float)(kt * 16 + quad * 4) * lg2);
    #pragma unroll
    for (int r = 0; r < 4; r++)
        drr[r] = exp2f(-(float)r * lg2);

    // Q fragments in registers (rows n0 + w*32 + rg*16 + ln)
    bf16x8 aq[2][4];
    #pragma unroll
    for (int rg = 0; rg < 2; rg++)
        #pragma unroll
        for (int ks = 0; ks < 4; ks++)
            aq[rg][ks] = *(const bf16x8*)&Qb[qbase
                + (size_t)(n0 + w * 32 + rg * 16 + ln) * 1024 + ks * 32 + quad * 8];

    f32x4 y[2][8];
    const f32x4 fzero = {0.f, 0.f, 0.f, 0.f};
    #pragma unroll
    for (int rg = 0; rg < 2; rg++)
        #pragma unroll
        for (int vt = 0; vt < 8; vt++) y[rg][vt] = fzero;

    // decay cutoff
    const float D = 34.0f / (-lg2);
    int cmin = (int)floorf(((float)n0 - 63.0f - D) * 0.015625f);
    if (cmin < 0) cmin = 0;
    const int cmax = 2 * qb + 1;

    ushort* Ssw = Ss + w * 2048;

    for (int c = cmin; c <= cmax; c++) {
        const int m0 = c * 64;
        // stage K (keys m0..m0+63) and V chunk via global_load_lds
        #pragma unroll
        for (int i = 0; i < 4; i++)
            gload16(Ksw + kbase + (size_t)(m0 + w * 16 + i * 4) * 128 + lane * 8,
                    &Ks[(w * 16 + i * 4) * 128]);
        #pragma unroll
        for (int i = 0; i < 4; i++)
            gload16(Vsw + vbase + (size_t)(w * 32 + i * 8 + (lane >> 3)) * 2048
                        + m0 + (lane & 7) * 8,
                    &Vs[(w * 32 + i * 8) * 64]);
        __syncthreads();

        const int mrel = m0 - n0;
        #pragma unroll
        for (int rg = 0; rg < 2; rg++) {
            // S^T: mfma(bk, aq) -> lane holds S[q=rg*16+ln][k=kt*16+quad*4+r]
            f32x4 s4[4];
            #pragma unroll
            for (int kt = 0; kt < 4; kt++) s4[kt] = fzero;
            #pragma unroll
            for (int ks = 0; ks < 4; ks++) {
                #pragma unroll
                for (int kt = 0; kt < 4; kt++) {
                    bf16x8 bk = *(const bf16x8*)&Ks[(kt * 16 + ln) * 128
                                    + (((ks * 4 + quad) ^ (ln & 7)) * 8)];
                    s4[kt] = __builtin_amdgcn_mfma_f32_16x16x32_bf16(bk, aq[rg][ks],
                                                                     s4[kt], 0, 0, 0);
                }
            }

            const int nloc = w * 32 + rg * 16 + ln;
            const float dq = exp2f((float)(n0 - m0 + nloc) * lg2);
            const int lr2 = rg * 16 + ln;
            #pragma unroll
            for (int kt = 0; kt < 4; kt++) {
                const float db = dq * dmk[kt];
                ushort4 pk;
                if (mrel >= 0) {
                    const int mb = mrel + kt * 16 + quad * 4;
                    pk.x = f2bf((mb + 0 <= nloc) ? s4[kt][0] * db * drr[0] : 0.f);
                    pk.y = f2bf((mb + 1 <= nloc) ? s4[kt][1] * db * drr[1] : 0.f);
                    pk.z = f2bf((mb + 2 <= nloc) ? s4[kt][2] * db * drr[2] : 0.f);
                    pk.w = f2bf((mb + 3 <= nloc) ? s4[kt][3] * db * drr[3] : 0.f);
                } else {
                    pk.x = f2bf(s4[kt][0] * db * drr[0]);
                    pk.y = f2bf(s4[kt][1] * db * drr[1]);
                    pk.z = f2bf(s4[kt][2] * db * drr[2]);
                    pk.w = f2bf(s4[kt][3] * db * drr[3]);
                }
                const int slot = (kt * 2 + (quad >> 1)) ^ (ln & 7);
                *(ushort4*)&Ssw[lr2 * 64 + slot * 8 + (quad & 1) * 4] = pk;
            }

            // Y += S * V (Ss rows wave-private)
            #pragma unroll
            for (int ks2 = 0; ks2 < 2; ks2++) {
                bf16x8 as = *(const bf16x8*)&Ssw[lr2 * 64
                                + (((ks2 * 4 + quad) ^ (ln & 7)) * 8)];
                #pragma unroll
                for (int vt = 0; vt < 8; vt++) {
                    bf16x8 bv = *(const bf16x8*)&Vs[(vt * 16 + ln) * 64
                                    + (((ks2 * 4 + quad) ^ (ln & 7)) * 8)];
                    y[rg][vt] = __builtin_amdgcn_mfma_f32_16x16x32_bf16(as, bv,
                                                                        y[rg][vt], 0, 0, 0);
                }
            }
        }
        __syncthreads();
    }

    // fused groupnorm + gate epilogue, coalesced via LDS transpose
    for (int rg = 0; rg < 2; rg++) {
        __syncthreads();
        #pragma unroll
        for (int r = 0; r < 4; r++) {
            float s = 0.f, sq = 0.f;
            #pragma unroll
            for (int vt = 0; vt < 8; vt++) {
                float v = y[rg][vt][r];
                s += v; sq += v * v;
            }
            #pragma unroll
            for (int off = 8; off >= 1; off >>= 1) {
                s  += __shfl_xor(s, off);
                sq += __shfl_xor(sq, off);
            }
            float mean = s * 0.0078125f;
            float var = sq * 0.0078125f - mean * mean;
            float rstd = rsqrtf(var + 1e-5f);
            const int lw = w * 16 + quad * 4 + r;
            #pragma unroll
            for (int vt = 0; vt < 8; vt++) {
                const int slot = (vt * 2 + (ln >> 3)) ^ (lw & 7);
                Zs[lw * 128 + slot * 8 + (ln & 7)] = f2bf((y[rg][vt][r] - mean) * rstd);
            }
        }
        __syncthreads();
        // coalesced affine + gate + store
        const int lr = t >> 2, p = t & 3;
        const int grow = n0 + (lr >> 4) * 32 + rg * 16 + (lr & 15);
        const size_t ob = ((size_t)(b * LL + grow)) * 1024 + h * 128 + p * 32;
        #pragma unroll
        for (int i = 0; i < 4; i++) {
            const int gidx = p * 4 + i;
            const int slot = gidx ^ (lr & 7);
            __align__(16) ushort yn8[8], g8[8], o8[8];
            *(uint4*)yn8 = *(uint4*)&Zs[lr * 128 + slot * 8];
            *(uint4*)g8  = *(const uint4*)&Gb[ob + i * 8];
            const int cb = h * 128 + p * 32 + i * 8;
            #pragma unroll
            for (int j = 0; j < 8; j++)
                o8[j] = f2bf((bf2f(yn8[j]) * gnw[cb + j] + gnb[cb + j]) * bf2f(g8[j]));
            *(uint4*)&Zb[ob + i * 8] = *(uint4*)o8;
        }
    }
}

// ---------------------------------------------------------------------------
extern "C" void kernel_launch(void* const* d_in, const int* in_sizes, int n_in,
                              void* d_out, int out_size, void* d_ws, size_t ws_size,
                              hipStream_t stream) {
    const float* X   = (const float*)d_in[0];
    const float* Wq  = (const float*)d_in[1];
    const float* Wk  = (const float*)d_in[2];
    const float* Wv  = (const float*)d_in[3];
    const float* Wg  = (const float*)d_in[4];
    const float* Wo  = (const float*)d_in[5];
    const float* gnw = (const float*)d_in[6];
    const float* gnb = (const float*)d_in[7];
    float* out = (float*)d_out;

    const size_t MB = 1u << 20;
    char* base = (char*)d_ws;
    float4* tbl = (float4*)base;                        // 2 MB
    ushort* Xb  = (ushort*)(base + 2 * MB);             // 16 MB
    ushort* Wqt = (ushort*)(base + 18 * MB);
    ushort* Wkt = (ushort*)(base + 20 * MB);
    ushort* Wvt = (ushort*)(base + 22 * MB);
    ushort* Wgt = (ushort*)(base + 24 * MB);
    ushort* Wot = (ushort*)(base + 26 * MB);
    ushort* Qb  = (ushort*)(base + 28 * MB);            // 16 MB (later Z)
    ushort* Kb  = (ushort*)(base + 44 * MB);            // 16 MB (swizzled)
    ushort* Gb  = (ushort*)(base + 60 * MB);            // 16 MB (silu applied)
    ushort* Vt  = (ushort*)(base + 76 * MB);            // 16 MB (swizzled) -> 92 MB
    ushort* Zb  = Qb;

    Gammas gp;
    for (int h = 0; h < 8; h++) {
        double lin = log(1.0 / 32.0) +
                     (log(1.0 / 512.0) - log(1.0 / 32.0)) * (double)h / 7.0;
        float gamma = 1.0f - expf((float)lin);
        gp.lg2[h] = log2f(gamma);
    }

    xpos_table_kernel<<<(LL * 64) / 256, 256, 0, stream>>>(tbl);
    cast_kernel<<<MM * 1024 / 1024, 256, 0, stream>>>(X, Xb);

    dim3 wgrid(16, 16);
    wtrans_kernel<<<wgrid, 256, 0, stream>>>(Wq, Wqt, 1);
    wtrans_kernel<<<wgrid, 256, 0, stream>>>(Wk, Wkt, 1);
    wtrans_kernel<<<wgrid, 256, 0, stream>>>(Wv, Wvt, 1);
    wtrans_kernel<<<wgrid, 256, 0, stream>>>(Wg, Wgt, 0);
    wtrans_kernel<<<wgrid, 256, 0, stream>>>(Wo, Wot, 0);

    // fused Q/K/V/G projections (K and V written in ret-ready swizzled layouts)
    MMArgs qa;
    qa.Bt[0] = Wqt; qa.Bt[1] = Wkt; qa.Bt[2] = Wvt; qa.Bt[3] = Wgt;
    qa.C[0] = Qb;   qa.C[1] = Kb;   qa.C[2] = Vt;   qa.C[3] = Gb;
    qa.emode[0] = 1; qa.emode[1] = 2; qa.emode[2] = 5; qa.emode[3] = 3;
    mm_kernel<<<dim3(32, 64), 256, 0, stream>>>(Xb, qa, tbl);

    // retention + fused groupnorm/gate -> Zb (bf16, overwrites Qb region)
    ret_kernel<<<dim3(16, 32), 256, 0, stream>>>(Qb, Kb, Vt, Gb, gnw, gnb, Zb, gp);

    MMArgs oa;
    oa.Bt[0] = Wot; oa.Bt[1] = Wot; oa.Bt[2] = Wot; oa.Bt[3] = Wot;
    oa.C[0] = out;  oa.C[1] = out;  oa.C[2] = out;  oa.C[3] = out;
    oa.emode[0] = 4; oa.emode[1] = 4; oa.emode[2] = 4; oa.emode[3] = 4;
    mm_kernel<<<dim3(8, 64), 256, 0, stream>>>(Zb, oa, tbl);
}

// Round 6
// 589.272 us; speedup vs baseline: 1.1987x; 1.1823x over previous
//
#include <hip/hip_runtime.h>
#include <cmath>

#define BB 4
#define LL 2048
#define DD 1024
#define HH 8
#define MM (BB * LL)   // 8192 rows

struct Gammas { float lg2[8]; };
struct MMArgs { const ushort* Bt[4]; void* C[4]; void* C2[4]; int emode[4]; };

typedef __attribute__((ext_vector_type(8))) short bf16x8;
typedef __attribute__((ext_vector_type(4))) float f32x4;

__device__ __forceinline__ ushort f2bf(float f) {
    uint u = __builtin_bit_cast(uint, f);
    uint r = (u + 0x7fffu + ((u >> 16) & 1u)) >> 16;
    return (ushort)r;
}
__device__ __forceinline__ float bf2f(ushort h) {
    uint u = ((uint)h) << 16;
    return __builtin_bit_cast(float, u);
}
__device__ __forceinline__ void gload16(const void* g, void* l) {
    __builtin_amdgcn_global_load_lds((const __attribute__((address_space(1))) void*)g,
                                     (__attribute__((address_space(3))) void*)l, 16, 0, 0);
}

// ---------------------------------------------------------------------------
// xpos table: tbl[l*64 + i] = {cos*scale, sin*scale, cos/scale, sin/scale}
// ---------------------------------------------------------------------------
__global__ void xpos_table_kernel(float4* __restrict__ tbl) {
    int tid = blockIdx.x * blockDim.x + threadIdx.x;
    if (tid >= LL * 64) return;
    int l = tid >> 6, i = tid & 63;
    float inv = powf(10000.0f, -(float)i / 64.0f);
    float ang = (float)l * inv;
    float s = sinf(ang), c = cosf(ang);
    float base = (2.0f * (float)i + 51.2f) / 179.2f;
    float sc = powf(base, (float)l / 512.0f);
    tbl[tid] = make_float4(c * sc, s * sc, c / sc, s / sc);
}

__global__ __launch_bounds__(256) void cast_kernel(const float* __restrict__ X,
                                                   ushort* __restrict__ Xb) {
    int i = (blockIdx.x * 256 + threadIdx.x) * 4;
    float4 v = *(const float4*)&X[i];
    ushort4 o;
    o.x = f2bf(v.x); o.y = f2bf(v.y); o.z = f2bf(v.z); o.w = f2bf(v.w);
    *(ushort4*)&Xb[i] = o;
}

// ---------------------------------------------------------------------------
// Weight transpose+cast: W[k][n] (flat or per-head (h,d,e)) -> Wt[n][k] bf16
// ---------------------------------------------------------------------------
__global__ __launch_bounds__(256) void wtrans_kernel(const float* __restrict__ W,
                                                     ushort* __restrict__ Wt, int perhead) {
    __shared__ float T[64][68];
    const int k0 = blockIdx.y * 64, n0 = blockIdx.x * 64;
    const int t = threadIdx.x;
    for (int f = t; f < 64 * 16; f += 256) {
        int kk = f >> 4, s = f & 15;
        int n = n0 + s * 4;
        size_t src = perhead ? (size_t)(n >> 7) * 131072 + (size_t)(k0 + kk) * 128 + (n & 127)
                             : (size_t)(k0 + kk) * 1024 + n;
        *(float4*)&T[kk][s * 4] = *(const float4*)&W[src];
    }
    __syncthreads();
    for (int f = t; f < 64 * 8; f += 256) {
        int n = f >> 3, s = f & 7;
        __align__(16) ushort tmp[8];
        #pragma unroll
        for (int j = 0; j < 8; j++) tmp[j] = f2bf(T[s * 8 + j][n]);
        *(uint4*)&Wt[(size_t)(n0 + n) * 1024 + k0 + s * 8] = *(uint4*)tmp;
    }
}

// ---------------------------------------------------------------------------
// bf16 MFMA GEMM: C = A[8192x1024] * Bt^T, multi-output (4 weight/out sets).
// emode: 1 xpos up -> Q plain bf16
//        2 xpos down -> Ksw [key][e-slot] AND Kt [e][key-chunk-slot] (C2)
//        3 silu -> plain bf16
//        4 plain -> fp32
//        5 V -> Vt_sw [b][vcol][chunk][slot] swizzled transposed layout
// ---------------------------------------------------------------------------
__global__ __launch_bounds__(256) void mm_kernel(
    const ushort* __restrict__ A, MMArgs args, const float4* __restrict__ tbl)
{
    __shared__ __align__(16) ushort As[128 * 32];
    __shared__ __align__(16) ushort Bs[128 * 32];
    const int t = threadIdx.x;
    const int w = t >> 6, lane = t & 63;
    const int ln = lane & 15, quad = lane >> 4;
    const int which = blockIdx.x >> 3;
    const ushort* Bt = args.Bt[which];
    void* Cv = args.C[which];
    void* Cv2 = args.C2[which];
    const int emode = args.emode[which];
    const int n0 = (blockIdx.x & 7) * 128, m0 = blockIdx.y * 128;
    const int wm = w & 1, wn = w >> 1;

    f32x4 acc[4][4];
    const f32x4 fzero = {0.f, 0.f, 0.f, 0.f};
    #pragma unroll
    for (int i = 0; i < 4; i++)
        #pragma unroll
        for (int j = 0; j < 4; j++) acc[i][j] = fzero;

    const int srow = w * 32 + (lane >> 2);
    const int scol = (((lane & 3) ^ ((lane >> 3) & 3))) * 8;   // source swizzle
    const ushort* ga  = A  + (size_t)(m0 + srow) * 1024 + scol;
    const ushort* ga2 = ga + 16 * 1024;
    const ushort* gb  = Bt + (size_t)(n0 + srow) * 1024 + scol;
    const ushort* gb2 = gb + 16 * 1024;
    ushort* la  = &As[(w * 32) * 32];
    ushort* la2 = &As[(w * 32 + 16) * 32];
    ushort* lb  = &Bs[(w * 32) * 32];
    ushort* lb2 = &Bs[(w * 32 + 16) * 32];

    const int fsw = (quad ^ ((ln >> 1) & 3)) * 8;   // swizzled frag col

    for (int kt = 0; kt < 1024; kt += 32) {
        gload16(ga + kt, la);
        gload16(ga2 + kt, la2);
        gload16(gb + kt, lb);
        gload16(gb2 + kt, lb2);
        __syncthreads();
        bf16x8 am[4], bn[4];
        #pragma unroll
        for (int i = 0; i < 4; i++)
            am[i] = *(const bf16x8*)&As[(wm * 64 + i * 16 + ln) * 32 + fsw];
        #pragma unroll
        for (int i = 0; i < 4; i++)
            bn[i] = *(const bf16x8*)&Bs[(wn * 64 + i * 16 + ln) * 32 + fsw];
        #pragma unroll
        for (int mi = 0; mi < 4; mi++)
            #pragma unroll
            for (int ni = 0; ni < 4; ni++)
                acc[mi][ni] = __builtin_amdgcn_mfma_f32_16x16x32_bf16(
                    am[mi], bn[ni], acc[mi][ni], 0, 0, 0);
        __syncthreads();
    }

    #pragma unroll
    for (int mi = 0; mi < 4; mi++) {
        #pragma unroll
        for (int ni = 0; ni < 4; ni++) {
            const int row0 = m0 + wm * 64 + mi * 16 + quad * 4;
            const int e = wn * 64 + ni * 16 + ln;
            const int col = n0 + e;
            if (emode == 5) {
                const int bb2 = row0 >> 11, l0 = row0 & (LL - 1);
                const int slot = ((l0 >> 3) & 7) ^ (col & 7);
                ushort4 pk;
                pk.x = f2bf(acc[mi][ni][0]); pk.y = f2bf(acc[mi][ni][1]);
                pk.z = f2bf(acc[mi][ni][2]); pk.w = f2bf(acc[mi][ni][3]);
                *(ushort4*)&((ushort*)Cv)[((size_t)(bb2 * 1024 + col)) * 2048
                                          + (l0 & ~63) + slot * 8 + (l0 & 7)] = pk;
                continue;
            }
            float vv[4];
            #pragma unroll
            for (int r = 0; r < 4; r++) {
                float v = acc[mi][ni][r];
                if (emode == 1 || emode == 2) {
                    float4 tt = tbl[(size_t)((row0 + r) & (LL - 1)) * 64 + (e >> 1)];
                    float cc = (emode == 1) ? tt.x : tt.z;
                    float ss = (emode == 1) ? tt.y : tt.w;
                    float partner = __shfl_xor(v, 1);
                    float rot = (e & 1) ? partner : -partner;
                    v = v * cc + rot * ss;
                } else if (emode == 3) {
                    v = v / (1.0f + expf(-v));
                }
                vv[r] = v;
            }
            if (emode == 4) {
                #pragma unroll
                for (int r = 0; r < 4; r++)
                    ((float*)Cv)[(size_t)(row0 + r) * 1024 + col] = vv[r];
            } else if (emode == 2) {
                const int bb2 = row0 >> 11, l0 = row0 & (LL - 1);
                const int hh = col >> 7, eh = col & 127;
                #pragma unroll
                for (int r = 0; r < 4; r++)
                    ((ushort*)Cv)[((size_t)(bb2 * 8 + hh) * 2048 + l0 + r) * 128
                                  + (size_t)(((eh >> 3) ^ ((l0 + r) & 7)) * 8) + (eh & 7)]
                        = f2bf(vv[r]);
                // Kt: [bh][e][key-chunk swizzled], ushort4 (4 consecutive keys)
                ushort4 pk;
                pk.x = f2bf(vv[0]); pk.y = f2bf(vv[1]);
                pk.z = f2bf(vv[2]); pk.w = f2bf(vv[3]);
                const int slot = ((l0 >> 3) & 7) ^ (eh & 7);
                *(ushort4*)&((ushort*)Cv2)[(size_t)(bb2 * 8 + hh) * (128 * 2048)
                        + (size_t)eh * 2048 + (l0 & ~63) + slot * 8 + (l0 & 7)] = pk;
            } else {
                #pragma unroll
                for (int r = 0; r < 4; r++)
                    ((ushort*)Cv)[(size_t)(row0 + r) * 1024 + col] = f2bf(vv[r]);
            }
        }
    }
}

// ---------------------------------------------------------------------------
// Pass 1: per (bh, qb): Ct[v][e] = sum_m gamma^{127-mloc} V[m][v] K[m][e]
// (m over the 128-key block). Output plain [v][e] bf16.
// ---------------------------------------------------------------------------
__global__ __launch_bounds__(256) void ret_pass1(
    const ushort* __restrict__ Kt, const ushort* __restrict__ Vsw,
    ushort* __restrict__ CS, Gammas gp)
{
    __shared__ __align__(16) ushort Vs[128 * 64];    // A: rows v, 64 keys
    __shared__ __align__(16) ushort Ks2[128 * 64];   // B: rows e, 64 keys
    const int t = threadIdx.x;
    const int w = t >> 6, lane = t & 63, ln = lane & 15, quad = lane >> 4;
    const int qb = blockIdx.x, bh = blockIdx.y;
    const int b = bh >> 3, h = bh & 7;
    const float lg2 = gp.lg2[h];
    const size_t vbase = ((size_t)b * 1024 + h * 128) * 2048;
    const size_t kbase = (size_t)bh * (128 * 2048);
    const int N0 = qb * 128;

    f32x4 acc[2][8];
    const f32x4 fzero = {0.f, 0.f, 0.f, 0.f};
    #pragma unroll
    for (int mi = 0; mi < 2; mi++)
        #pragma unroll
        for (int ni = 0; ni < 8; ni++) acc[mi][ni] = fzero;

    float gj[8];
    #pragma unroll
    for (int j = 0; j < 8; j++) gj[j] = exp2f(-lg2 * (float)j);

    for (int sc = 0; sc < 2; sc++) {
        const int m0 = N0 + sc * 64;
        #pragma unroll
        for (int i = 0; i < 4; i++)
            gload16(Vsw + vbase + (size_t)(w * 32 + i * 8 + (lane >> 3)) * 2048
                        + m0 + (lane & 7) * 8,
                    &Vs[(w * 32 + i * 8) * 64]);
        #pragma unroll
        for (int i = 0; i < 4; i++)
            gload16(Kt + kbase + (size_t)(w * 32 + i * 8 + (lane >> 3)) * 2048
                        + m0 + (lane & 7) * 8,
                    &Ks2[(w * 32 + i * 8) * 64]);
        __syncthreads();
        #pragma unroll
        for (int ks = 0; ks < 2; ks++) {
            const float fb = exp2f(lg2 * (float)(127 - sc * 64 - ks * 32 - quad * 8));
            bf16x8 av[2];
            #pragma unroll
            for (int mi = 0; mi < 2; mi++) {
                bf16x8 raw = *(const bf16x8*)&Vs[(w * 32 + mi * 16 + ln) * 64
                                + (((ks * 4 + quad) ^ (ln & 7)) * 8)];
                #pragma unroll
                for (int j = 0; j < 8; j++)
                    av[mi][j] = (short)f2bf(bf2f((ushort)raw[j]) * fb * gj[j]);
            }
            #pragma unroll
            for (int ni = 0; ni < 8; ni++) {
                bf16x8 be = *(const bf16x8*)&Ks2[(ni * 16 + ln) * 64
                                + (((ks * 4 + quad) ^ (ln & 7)) * 8)];
                #pragma unroll
                for (int mi = 0; mi < 2; mi++)
                    acc[mi][ni] = __builtin_amdgcn_mfma_f32_16x16x32_bf16(
                        av[mi], be, acc[mi][ni], 0, 0, 0);
            }
        }
        __syncthreads();
    }

    const size_t cbase = ((size_t)(bh * 16 + qb)) * 16384;
    #pragma unroll
    for (int mi = 0; mi < 2; mi++)
        #pragma unroll
        for (int ni = 0; ni < 8; ni++)
            #pragma unroll
            for (int r = 0; r < 4; r++) {
                const int v = w * 32 + mi * 16 + quad * 4 + r;
                const int e = ni * 16 + ln;
                CS[cbase + v * 128 + e] = f2bf(acc[mi][ni][r]);
            }
}

// ---------------------------------------------------------------------------
// Scan: S_0 = 0; S_{qb} = g^128 * S_{qb-1} + C_{qb-1}. In place over CS:
// reads plain C rows, overwrites with slot-swizzled bf16 St (safe: each
// 16-lane group owns its v-rows; reads precede writes in wave program order).
// ---------------------------------------------------------------------------
__global__ __launch_bounds__(256) void ret_scan(ushort* __restrict__ CS, Gammas gp)
{
    const int t = threadIdx.x;
    const int bh = blockIdx.y;
    const float lg2 = gp.lg2[bh & 7];
    const float g128 = exp2f(128.0f * lg2);
    const int v = blockIdx.x * 16 + (t >> 4);
    const int gr = t & 15;
    const int slot = gr ^ (v & 7);
    const size_t base = (size_t)bh * 16 * 16384;
    float st[8] = {0.f, 0.f, 0.f, 0.f, 0.f, 0.f, 0.f, 0.f};
    for (int qb = 0; qb < 16; qb++) {
        const size_t rb = base + (size_t)qb * 16384 + (size_t)v * 128;
        __align__(16) ushort c8[8];
        *(uint4*)c8 = *(const uint4*)&CS[rb + gr * 8];
        __align__(16) ushort s8[8];
        #pragma unroll
        for (int j = 0; j < 8; j++) s8[j] = f2bf(st[j]);
        *(uint4*)&CS[rb + slot * 8] = *(uint4*)s8;
        #pragma unroll
        for (int j = 0; j < 8; j++) st[j] = st[j] * g128 + bf2f(c8[j]);
    }
}

// ---------------------------------------------------------------------------
// Pass 2: per (bh, qb): Y = (Q*g^{nloc+1}) @ St_qb + intra-causal retention
// over the 2 local 64-key chunks; fused groupnorm + gate -> bf16 Z.
// ---------------------------------------------------------------------------
__global__ __launch_bounds__(256, 3) void ret_pass2(
    const ushort* __restrict__ Qb, const ushort* __restrict__ Ksw,
    const ushort* __restrict__ Vsw, const ushort* __restrict__ Stp,
    const ushort* __restrict__ Gb,
    const float* __restrict__ gnw, const float* __restrict__ gnb,
    ushort* __restrict__ Zb, Gammas gp)
{
    __shared__ __align__(16) ushort smem[24576];   // 48 KB
    ushort* Sts = smem;               // 128 x 128 (St staged)        32 KB
    ushort* Ks  = smem;               // 64 keys x 128 el             16 KB
    ushort* Vs  = smem + 8192;        // 128 vcol x 64 keys           16 KB
    ushort* Ss  = smem + 16384;       // 4 waves x 32 rows x 64 keys  16 KB
    ushort* Zs  = smem + 16384;       // epilogue alias 64 x 128      16 KB

    const int t = threadIdx.x;
    const int w = t >> 6, lane = t & 63, ln = lane & 15, quad = lane >> 4;
    const int qb = blockIdx.x, bh = blockIdx.y;
    const int b = bh >> 3, h = bh & 7;
    const int n0 = qb * 128;
    const float lg2 = gp.lg2[h];

    const size_t qbase = (size_t)(b * LL) * 1024 + (size_t)h * 128;
    const size_t kbase = (size_t)bh * (2048 * 128);
    const size_t vbase = ((size_t)b * 1024 + h * 128) * 2048;
    const size_t sbase = ((size_t)(bh * 16 + qb)) * 16384;

    // Q fragments (raw)
    bf16x8 aq[2][4];
    #pragma unroll
    for (int rg = 0; rg < 2; rg++)
        #pragma unroll
        for (int ks = 0; ks < 4; ks++)
            aq[rg][ks] = *(const bf16x8*)&Qb[qbase
                + (size_t)(n0 + w * 32 + rg * 16 + ln) * 1024 + ks * 32 + quad * 8];

    // stage St (swizzled rows, layout-preserving copy)
    #pragma unroll
    for (int i = 0; i < 8; i++)
        gload16(Stp + sbase + (size_t)(w * 32 + i * 4 + (lane >> 4)) * 128
                    + (lane & 15) * 8,
                &Sts[(w * 32 + i * 4) * 128]);

    float dmk[4], drr[4];
    #pragma unroll
    for (int kt = 0; kt < 4; kt++)
        dmk[kt] = exp2f(-(float)(kt * 16 + quad * 4) * lg2);
    #pragma unroll
    for (int r = 0; r < 4; r++)
        drr[r] = exp2f(-(float)r * lg2);

    f32x4 y[2][8];
    const f32x4 fzero = {0.f, 0.f, 0.f, 0.f};
    #pragma unroll
    for (int rg = 0; rg < 2; rg++)
        #pragma unroll
        for (int vt = 0; vt < 8; vt++) y[rg][vt] = fzero;

    __syncthreads();

    // Y = Qd @ St
    #pragma unroll
    for (int rg = 0; rg < 2; rg++) {
        const float qd = exp2f(lg2 * (float)(w * 32 + rg * 16 + ln + 1));
        bf16x8 aqd[4];
        #pragma unroll
        for (int ks = 0; ks < 4; ks++)
            #pragma unroll
            for (int j = 0; j < 8; j++)
                aqd[ks][j] = (short)f2bf(bf2f((ushort)aq[rg][ks][j]) * qd);
        #pragma unroll
        for (int ks = 0; ks < 4; ks++)
            #pragma unroll
            for (int vt = 0; vt < 8; vt++) {
                bf16x8 bv = *(const bf16x8*)&Sts[(vt * 16 + ln) * 128
                                + (((ks * 4 + quad) ^ (ln & 7)) * 8)];
                y[rg][vt] = __builtin_amdgcn_mfma_f32_16x16x32_bf16(
                    aqd[ks], bv, y[rg][vt], 0, 0, 0);
            }
    }
    __syncthreads();

    // intra chunks
    ushort* Ssw = Ss + w * 2048;
    for (int c = 0; c < 2; c++) {
        const int m0 = n0 + c * 64, mrel = c * 64;
        #pragma unroll
        for (int i = 0; i < 4; i++)
            gload16(Ksw + kbase + (size_t)(m0 + w * 16 + i * 4) * 128 + lane * 8,
                    &Ks[(w * 16 + i * 4) * 128]);
        #pragma unroll
        for (int i = 0; i < 4; i++)
            gload16(Vsw + vbase + (size_t)(w * 32 + i * 8 + (lane >> 3)) * 2048
                        + m0 + (lane & 7) * 8,
                    &Vs[(w * 32 + i * 8) * 64]);
        __syncthreads();

        #pragma unroll
        for (int rg = 0; rg < 2; rg++) {
            const int tbase = w * 32 + rg * 16;
            if (tbase + 15 < mrel) continue;   // tile fully masked (wave-uniform)
            f32x4 s4[4];
            #pragma unroll
            for (int kt = 0; kt < 4; kt++) s4[kt] = fzero;
            #pragma unroll
            for (int ks = 0; ks < 4; ks++) {
                #pragma unroll
                for (int kt = 0; kt < 4; kt++) {
                    bf16x8 bk = *(const bf16x8*)&Ks[(kt * 16 + ln) * 128
                                    + (((ks * 4 + quad) ^ (ln & 7)) * 8)];
                    s4[kt] = __builtin_amdgcn_mfma_f32_16x16x32_bf16(
                        bk, aq[rg][ks], s4[kt], 0, 0, 0);
                }
            }
            const int nloc = tbase + ln;
            const float dq = exp2f((float)(nloc - mrel) * lg2);
            const int lr2 = rg * 16 + ln;
            #pragma unroll
            for (int kt = 0; kt < 4; kt++) {
                const float db = dq * dmk[kt];
                const int mb = mrel + kt * 16 + quad * 4;
                ushort4 pk;
                pk.x = f2bf((mb + 0 <= nloc) ? s4[kt][0] * db * drr[0] : 0.f);
                pk.y = f2bf((mb + 1 <= nloc) ? s4[kt][1] * db * drr[1] : 0.f);
                pk.z = f2bf((mb + 2 <= nloc) ? s4[kt][2] * db * drr[2] : 0.f);
                pk.w = f2bf((mb + 3 <= nloc) ? s4[kt][3] * db * drr[3] : 0.f);
                const int slot = (kt * 2 + (quad >> 1)) ^ (ln & 7);
                *(ushort4*)&Ssw[lr2 * 64 + slot * 8 + (quad & 1) * 4] = pk;
            }
            #pragma unroll
            for (int ks2 = 0; ks2 < 2; ks2++) {
                bf16x8 as = *(const bf16x8*)&Ssw[lr2 * 64
                                + (((ks2 * 4 + quad) ^ (ln & 7)) * 8)];
                #pragma unroll
                for (int vt = 0; vt < 8; vt++) {
                    bf16x8 bv = *(const bf16x8*)&Vs[(vt * 16 + ln) * 64
                                    + (((ks2 * 4 + quad) ^ (ln & 7)) * 8)];
                    y[rg][vt] = __builtin_amdgcn_mfma_f32_16x16x32_bf16(
                        as, bv, y[rg][vt], 0, 0, 0);
                }
            }
        }
        __syncthreads();
    }

    // fused groupnorm + gate epilogue, coalesced via LDS transpose
    for (int rg = 0; rg < 2; rg++) {
        __syncthreads();
        #pragma unroll
        for (int r = 0; r < 4; r++) {
            float s = 0.f, sq = 0.f;
            #pragma unroll
            for (int vt = 0; vt < 8; vt++) {
                float v = y[rg][vt][r];
                s += v; sq += v * v;
            }
            #pragma unroll
            for (int off = 8; off >= 1; off >>= 1) {
                s  += __shfl_xor(s, off);
                sq += __shfl_xor(sq, off);
            }
            float mean = s * 0.0078125f;
            float var = sq * 0.0078125f - mean * mean;
            float rstd = rsqrtf(var + 1e-5f);
            const int lw = w * 16 + quad * 4 + r;
            #pragma unroll
            for (int vt = 0; vt < 8; vt++) {
                const int slot = (vt * 2 + (ln >> 3)) ^ (lw & 7);
                Zs[lw * 128 + slot * 8 + (ln & 7)] = f2bf((y[rg][vt][r] - mean) * rstd);
            }
        }
        __syncthreads();
        const int lr = t >> 2, p = t & 3;
        const int grow = n0 + (lr >> 4) * 32 + rg * 16 + (lr & 15);
        const size_t ob = ((size_t)(b * LL + grow)) * 1024 + h * 128 + p * 32;
        #pragma unroll
        for (int i = 0; i < 4; i++) {
            const int gidx = p * 4 + i;
            const int slot = gidx ^ (lr & 7);
            __align__(16) ushort yn8[8], g8[8], o8[8];
            *(uint4*)yn8 = *(uint4*)&Zs[lr * 128 + slot * 8];
            *(uint4*)g8  = *(const uint4*)&Gb[ob + i * 8];
            const int cb = h * 128 + p * 32 + i * 8;
            #pragma unroll
            for (int j = 0; j < 8; j++)
                o8[j] = f2bf((bf2f(yn8[j]) * gnw[cb + j] + gnb[cb + j]) * bf2f(g8[j]));
            *(uint4*)&Zb[ob + i * 8] = *(uint4*)o8;
        }
    }
}

// ---------------------------------------------------------------------------
extern "C" void kernel_launch(void* const* d_in, const int* in_sizes, int n_in,
                              void* d_out, int out_size, void* d_ws, size_t ws_size,
                              hipStream_t stream) {
    const float* X   = (const float*)d_in[0];
    const float* Wq  = (const float*)d_in[1];
    const float* Wk  = (const float*)d_in[2];
    const float* Wv  = (const float*)d_in[3];
    const float* Wg  = (const float*)d_in[4];
    const float* Wo  = (const float*)d_in[5];
    const float* gnw = (const float*)d_in[6];
    const float* gnb = (const float*)d_in[7];
    float* out = (float*)d_out;

    const size_t MB = 1u << 20;
    char* base = (char*)d_ws;
    float4* tbl = (float4*)base;                        // 2 MB
    ushort* Xb  = (ushort*)(base + 2 * MB);             // 16 MB
    ushort* Wqt = (ushort*)(base + 18 * MB);
    ushort* Wkt = (ushort*)(base + 20 * MB);
    ushort* Wvt = (ushort*)(base + 22 * MB);
    ushort* Wgt = (ushort*)(base + 24 * MB);
    ushort* Wot = (ushort*)(base + 26 * MB);
    ushort* Qb  = (ushort*)(base + 28 * MB);            // 16 MB (later Z)
    ushort* Kb  = (ushort*)(base + 44 * MB);            // 16 MB Ksw
    ushort* Gb  = (ushort*)(base + 60 * MB);            // 16 MB (silu applied)
    ushort* Vt  = (ushort*)(base + 76 * MB);            // 16 MB Vsw
    ushort* Kt  = (ushort*)(base + 92 * MB);            // 16 MB K transposed
    ushort* CS  = (ushort*)(base + 108 * MB);           // 16 MB C/St (in-place)
    ushort* Zb  = Qb;                                   // -> 124 MB total

    Gammas gp;
    for (int h = 0; h < 8; h++) {
        double lin = log(1.0 / 32.0) +
                     (log(1.0 / 512.0) - log(1.0 / 32.0)) * (double)h / 7.0;
        float gamma = 1.0f - expf((float)lin);
        gp.lg2[h] = log2f(gamma);
    }

    xpos_table_kernel<<<(LL * 64) / 256, 256, 0, stream>>>(tbl);
    cast_kernel<<<MM * 1024 / 1024, 256, 0, stream>>>(X, Xb);

    dim3 wgrid(16, 16);
    wtrans_kernel<<<wgrid, 256, 0, stream>>>(Wq, Wqt, 1);
    wtrans_kernel<<<wgrid, 256, 0, stream>>>(Wk, Wkt, 1);
    wtrans_kernel<<<wgrid, 256, 0, stream>>>(Wv, Wvt, 1);
    wtrans_kernel<<<wgrid, 256, 0, stream>>>(Wg, Wgt, 0);
    wtrans_kernel<<<wgrid, 256, 0, stream>>>(Wo, Wot, 0);

    // fused Q/K/V/G projections (K dual-layout, V transposed-swizzled)
    MMArgs qa;
    qa.Bt[0] = Wqt; qa.Bt[1] = Wkt; qa.Bt[2] = Wvt; qa.Bt[3] = Wgt;
    qa.C[0] = Qb;   qa.C[1] = Kb;   qa.C[2] = Vt;   qa.C[3] = Gb;
    qa.C2[0] = 0;   qa.C2[1] = Kt;  qa.C2[2] = 0;   qa.C2[3] = 0;
    qa.emode[0] = 1; qa.emode[1] = 2; qa.emode[2] = 5; qa.emode[3] = 3;
    mm_kernel<<<dim3(32, 64), 256, 0, stream>>>(Xb, qa, tbl);

    // chunkwise retention: per-block K^T V summaries -> decayed prefix scan
    // -> intra + Q@State, fused groupnorm/gate
    ret_pass1<<<dim3(16, 32), 256, 0, stream>>>(Kt, Vt, CS, gp);
    ret_scan<<<dim3(8, 32), 256, 0, stream>>>(CS, gp);
    ret_pass2<<<dim3(16, 32), 256, 0, stream>>>(Qb, Kb, Vt, CS, Gb, gnw, gnb, Zb, gp);

    MMArgs oa;
    oa.Bt[0] = Wot; oa.Bt[1] = Wot; oa.Bt[2] = Wot; oa.Bt[3] = Wot;
    oa.C[0] = out;  oa.C[1] = out;  oa.C[2] = out;  oa.C[3] = out;
    oa.C2[0] = 0;   oa.C2[1] = 0;   oa.C2[2] = 0;   oa.C2[3] = 0;
    oa.emode[0] = 4; oa.emode[1] = 4; oa.emode[2] = 4; oa.emode[3] = 4;
    mm_kernel<<<dim3(8, 64), 256, 0, stream>>>(Zb, oa, tbl);
}